// Round 10
// baseline (88.667 us; speedup 1.0000x reference)
//
#include <hip/hip_runtime.h>

typedef float v2f __attribute__((ext_vector_type(2)));
typedef _Float16 h2 __attribute__((ext_vector_type(2)));   // packed f16 pair, 1 VGPR

constexpr int NQ = 4;
constexpr int DIM = 16;          // 2^NQ
constexpr float MARGIN = 0.3f;
constexpr float INV2PI = 0.15915494309189535f;

__device__ __forceinline__ v2f mk2(float x, float y) { v2f r; r.x = x; r.y = y; return r; }

// plain complex multiply; negations fold into FMA source modifiers (no extra regs)
__device__ __forceinline__ v2f cmul(v2f a, v2f b) {
  return mk2(a.x * b.x - a.y * b.y, a.x * b.y + a.y * b.x);
}

__device__ __forceinline__ void sincos_hw(float rev, float& s, float& c) {
  s = __builtin_amdgcn_sinf(rev);   // input in revolutions
  c = __builtin_amdgcn_cosf(rev);
}

// CNOT ladder CNOT(q,q+1), q=0..2; qubit q == flat bit (3-q). Free permutation.
__device__ __forceinline__ void cnot_ladder(v2f s[DIM]) {
#pragma unroll
  for (int q = 0; q < NQ - 1; ++q) {
    const int pc = 1 << (NQ - 1 - q);
    const int pt = 1 << (NQ - 2 - q);
#pragma unroll
    for (int i = 0; i < DIM; ++i) {
      if ((i & pc) && !(i & pt)) {
        const int j = i | pt;
        v2f t = s[i]; s[i] = s[j]; s[j] = t;
      }
    }
  }
}

// Layer-1 product state (RZ as diag(1,e^{i z}), global phase dropped) + CNOT
// ladder + layer-2 RY butterflies. Final RZ merged into the overlap; final
// CNOT ladder cancels in the overlap.
__device__ __forceinline__ void sim_core(const float ry[8], const float rz[8], v2f s[DIM]) {
  float c0[NQ]; v2f p1[NQ];
#pragma unroll
  for (int q = 0; q < NQ; ++q) {
    float sy, cy; sincos_hw(ry[q] * (0.5f * INV2PI), sy, cy);
    float sz, cz; sincos_hw(rz[q] * INV2PI, sz, cz);
    c0[q] = cy;
    p1[q] = mk2(sy * cz, sy * sz);
  }
  v2f t2[4];
  t2[0] = mk2(c0[0] * c0[1], 0.0f);
  t2[1] = c0[0] * p1[1];
  t2[2] = c0[1] * p1[0];
  t2[3] = cmul(p1[0], p1[1]);
  v2f t3[8];
#pragma unroll
  for (int k = 0; k < 4; ++k) {
    t3[2*k]   = t2[k] * c0[2];
    t3[2*k+1] = cmul(t2[k], p1[2]);
  }
#pragma unroll
  for (int k = 0; k < 8; ++k) {
    s[2*k]   = t3[k] * c0[3];
    s[2*k+1] = cmul(t3[k], p1[3]);
  }

  cnot_ladder(s);

#pragma unroll
  for (int q = 0; q < NQ; ++q) {
    const int bit = 1 << (NQ - 1 - q);
    float sy, cy; sincos_hw(ry[4 + q] * (0.5f * INV2PI), sy, cy);
#pragma unroll
    for (int i = 0; i < DIM; ++i) {
      if (i & bit) continue;
      const int j = i | bit;
      const v2f a0 = s[i], a1 = s[j];
      s[i] = cy * a0 - sy * a1;
      s[j] = sy * a0 + cy * a1;
    }
  }
}

// |<a| PΔ |x>|^2 with anchor in packed f16 and PΔ folded in via the per-qubit
// contraction tree. Streams the elementwise conj(a)*x products (no d[16] array).
__device__ __forceinline__ float fid_tree_h(const h2 a[DIM], const v2f x[DIM],
                                            const float dz[NQ]) {
  v2f ph[NQ];
#pragma unroll
  for (int q = 0; q < NQ; ++q) {
    float s, c; sincos_hw(dz[q] * INV2PI, s, c);
    ph[q] = mk2(c, s);
  }
  v2f e[8];
#pragma unroll
  for (int j = 0; j < 8; ++j) {
    const int i0 = 2*j, i1 = 2*j + 1;
    const float a0r = (float)a[i0].x, a0i = (float)a[i0].y;
    const float a1r = (float)a[i1].x, a1i = (float)a[i1].y;
    const v2f d0 = mk2(a0r * x[i0].x + a0i * x[i0].y, a0r * x[i0].y - a0i * x[i0].x);
    const v2f d1 = mk2(a1r * x[i1].x + a1i * x[i1].y, a1r * x[i1].y - a1i * x[i1].x);
    e[j] = d0 + cmul(d1, ph[3]);
  }
  v2f f[4];
#pragma unroll
  for (int k = 0; k < 4; ++k) f[k] = e[2*k] + cmul(e[2*k+1], ph[2]);
  v2f g[2];
#pragma unroll
  for (int m = 0; m < 2; ++m) g[m] = f[2*m] + cmul(f[2*m+1], ph[1]);
  const v2f ov = g[0] + cmul(g[1], ph[0]);
  return ov.x * ov.x + ov.y * ov.y;
}

__device__ __forceinline__ void load8(const float* __restrict__ p, int b, float a[8]) {
  const float4* v = reinterpret_cast<const float4*>(p) + (size_t)b * 2;
  float4 x0 = v[0], x1 = v[1];
  a[0]=x0.x; a[1]=x0.y; a[2]=x0.z; a[3]=x0.w;
  a[4]=x1.x; a[5]=x1.y; a[6]=x1.z; a[7]=x1.w;
}

__global__ __launch_bounds__(256, 8) void triplet_main(
    const float* __restrict__ a_ry, const float* __restrict__ a_rz,
    const float* __restrict__ p_ry, const float* __restrict__ p_rz,
    const float* __restrict__ n_ry, const float* __restrict__ n_rz,
    float* __restrict__ block_sums, int batch) {
  const int b = blockIdx.x * blockDim.x + threadIdx.x;

  float loss = 0.0f;
  if (b < batch) {
    float ry[8], rz[8], arz2[NQ];

    // anchor: simulate in f32, store packed f16 (16 VGPRs, read-only afterwards)
    load8(a_ry, b, ry); load8(a_rz, b, rz);
#pragma unroll
    for (int q = 0; q < NQ; ++q) arz2[q] = rz[4 + q];
    h2 ah[DIM];
    {
      v2f tmp[DIM];
      sim_core(ry, rz, tmp);
#pragma unroll
      for (int i = 0; i < DIM; ++i) {
        h2 v; v.x = (_Float16)tmp[i].x; v.y = (_Float16)tmp[i].y;
        ah[i] = v;
      }
    }

    // positive
    load8(p_ry, b, ry); load8(p_rz, b, rz);
    v2f xs[DIM];
    sim_core(ry, rz, xs);
    float dz[NQ];
#pragma unroll
    for (int q = 0; q < NQ; ++q) dz[q] = rz[4 + q] - arz2[q];
    const float fid_pos = fid_tree_h(ah, xs, dz);

    // negative (reuse xs)
    load8(n_ry, b, ry); load8(n_rz, b, rz);
    sim_core(ry, rz, xs);
#pragma unroll
    for (int q = 0; q < NQ; ++q) dz[q] = rz[4 + q] - arz2[q];
    const float fid_neg = fid_tree_h(ah, xs, dz);

    loss = fmaxf(MARGIN - fid_pos + fid_neg, 0.0f);
  }

  // wave (64) reduce, then LDS across the 4 waves
#pragma unroll
  for (int off = 32; off >= 1; off >>= 1)
    loss += __shfl_down(loss, off, 64);

  __shared__ float wsum[4];
  const int lane = threadIdx.x & 63;
  const int wid  = threadIdx.x >> 6;
  if (lane == 0) wsum[wid] = loss;
  __syncthreads();
  if (threadIdx.x == 0) {
    block_sums[blockIdx.x] = wsum[0] + wsum[1] + wsum[2] + wsum[3];
  }
}

__global__ __launch_bounds__(256) void triplet_reduce(
    const float* __restrict__ block_sums, int nblocks, float* __restrict__ out, float inv_batch) {
  float s = 0.0f;
  for (int i = threadIdx.x; i < nblocks; i += 256) s += block_sums[i];
#pragma unroll
  for (int off = 32; off >= 1; off >>= 1)
    s += __shfl_down(s, off, 64);

  __shared__ float wsum[4];
  const int lane = threadIdx.x & 63;
  const int wid  = threadIdx.x >> 6;
  if (lane == 0) wsum[wid] = s;
  __syncthreads();
  if (threadIdx.x == 0) {
    out[0] = (wsum[0] + wsum[1] + wsum[2] + wsum[3]) * inv_batch;
  }
}

extern "C" void kernel_launch(void* const* d_in, const int* in_sizes, int n_in,
                              void* d_out, int out_size, void* d_ws, size_t ws_size,
                              hipStream_t stream) {
  const float* a_ry = (const float*)d_in[0];
  const float* a_rz = (const float*)d_in[1];
  const float* p_ry = (const float*)d_in[2];
  const float* p_rz = (const float*)d_in[3];
  const float* n_ry = (const float*)d_in[4];
  const float* n_rz = (const float*)d_in[5];
  float* out = (float*)d_out;

  const int batch = in_sizes[0] / 8;            // NL*NQ = 8 angles per element
  const int nblocks = (batch + 255) / 256;      // 2048
  float* block_sums = (float*)d_ws;

  triplet_main<<<nblocks, 256, 0, stream>>>(a_ry, a_rz, p_ry, p_rz, n_ry, n_rz,
                                            block_sums, batch);
  triplet_reduce<<<1, 256, 0, stream>>>(block_sums, nblocks, out, 1.0f / (float)batch);
}

// Round 11
// 39.493 us; speedup vs baseline: 2.2451x; 2.2451x over previous
//
#include <hip/hip_runtime.h>

typedef float v2f __attribute__((ext_vector_type(2)));
typedef _Float16 h2 __attribute__((ext_vector_type(2)));   // packed f16 pair, 1 VGPR

constexpr int NQ = 4;
constexpr float MARGIN = 0.3f;
constexpr float INV2PI = 0.15915494309189535f;

__device__ __forceinline__ v2f mk2(float x, float y) { v2f r; r.x = x; r.y = y; return r; }

__device__ __forceinline__ v2f cmul(v2f a, v2f b) {
  return mk2(a.x * b.x - a.y * b.y, a.x * b.y + a.y * b.x);
}

__device__ __forceinline__ void sincos_hw(float rev, float& s, float& c) {
  s = __builtin_amdgcn_sinf(rev);   // input in revolutions
  c = __builtin_amdgcn_cosf(rev);
}

// Lane-pair split: lane parity p owns the 8 amplitudes with amp-bit3 == p.
// Local index m = (b2,b1,b0); global amp i = p*8 + m.
// Layer-1 product state with the inter-layer CNOT ladder folded in:
//   amp(p,b2,b1,b0) = u0[p] * u1[b2^p] * u2[b1^b2] * u3[b0^b1]
// (u_q = (cos(ry_q/2), sin(ry_q/2) e^{i rz_q}); global phase dropped.)
// Then layer-2 RY: qubits 1..3 lane-local, qubit 0 via shfl_xor(1).
// Final RZ merged into the overlap; final CNOT ladder cancels there.
__device__ __forceinline__ void sim_half(const int p, const float ry[8], const float rz[8],
                                         v2f s[8]) {
  float sy0, cy0; sincos_hw(ry[0] * (0.5f * INV2PI), sy0, cy0);
  float sz0, cz0; sincos_hw(rz[0] * INV2PI, sz0, cz0);
  const v2f F0 = p ? mk2(sy0 * cz0, sy0 * sz0) : mk2(cy0, 0.0f);

  float sy, cy, sz, cz;
  sincos_hw(ry[1] * (0.5f * INV2PI), sy, cy); sincos_hw(rz[1] * INV2PI, sz, cz);
  const float c1 = cy; const v2f p1 = mk2(sy * cz, sy * sz);
  sincos_hw(ry[2] * (0.5f * INV2PI), sy, cy); sincos_hw(rz[2] * INV2PI, sz, cz);
  const float c2 = cy; const v2f p2 = mk2(sy * cz, sy * sz);
  sincos_hw(ry[3] * (0.5f * INV2PI), sy, cy); sincos_hw(rz[3] * INV2PI, sz, cz);
  const float c3 = cy; const v2f p3 = mk2(sy * cz, sy * sz);

  // T[b2] = F0 * u1[b2^p]
  const v2f Ta = F0 * c1;        // F0*u1[0]
  const v2f Tb = cmul(F0, p1);   // F0*u1[1]
  const v2f T0 = p ? Tb : Ta;
  const v2f T1 = p ? Ta : Tb;
  // L[b2][b1] = T[b2] * u2[b1^b2]
  const v2f L00 = T0 * c2;
  const v2f L01 = cmul(T0, p2);
  const v2f L10 = cmul(T1, p2);
  const v2f L11 = T1 * c2;
  // s[m] = L[b2][b1] * u3[b0^b1]
  s[0] = L00 * c3;  s[1] = cmul(L00, p3);
  s[2] = cmul(L01, p3);  s[3] = L01 * c3;
  s[4] = L10 * c3;  s[5] = cmul(L10, p3);
  s[6] = cmul(L11, p3);  s[7] = L11 * c3;

  // layer-2 RY, qubit 1 (local bit2): pairs (m, m+4)
  sincos_hw(ry[5] * (0.5f * INV2PI), sy, cy);
#pragma unroll
  for (int m = 0; m < 4; ++m) {
    const v2f a0 = s[m], a1 = s[m + 4];
    s[m]     = cy * a0 - sy * a1;
    s[m + 4] = sy * a0 + cy * a1;
  }
  // qubit 2 (local bit1): pairs (m, m+2), m in {0,1,4,5}
  sincos_hw(ry[6] * (0.5f * INV2PI), sy, cy);
#pragma unroll
  for (int k = 0; k < 4; ++k) {
    const int m = (k & 1) | ((k & 2) << 1);   // 0,1,4,5
    const v2f a0 = s[m], a1 = s[m + 2];
    s[m]     = cy * a0 - sy * a1;
    s[m + 2] = sy * a0 + cy * a1;
  }
  // qubit 3 (local bit0): pairs (m, m+1), m in {0,2,4,6}
  sincos_hw(ry[7] * (0.5f * INV2PI), sy, cy);
#pragma unroll
  for (int k = 0; k < 4; ++k) {
    const int m = 2 * k;
    const v2f a0 = s[m], a1 = s[m + 1];
    s[m]     = cy * a0 - sy * a1;
    s[m + 1] = sy * a0 + cy * a1;
  }
  // qubit 0 (amp bit3 = lane parity): cross-lane butterfly.
  // lane p: s' = cy*own + ss*partner, ss = p ? +sy : -sy
  sincos_hw(ry[4] * (0.5f * INV2PI), sy, cy);
  const float ss = p ? sy : -sy;
#pragma unroll
  for (int m = 0; m < 8; ++m) {
    const float prx = __shfl_xor(s[m].x, 1);
    const float pry_ = __shfl_xor(s[m].y, 1);
    s[m] = mk2(cy * s[m].x + ss * prx, cy * s[m].y + ss * pry_);
  }
}

// |<a| PD |x>|^2, anchor half in packed f16. PD = merged final-RZ delta phases:
// qubit0 phase (dz[0]) applies iff p==1; qubits 1..3 contract in-lane over
// bits b2,b1,b0. Cross-lane combine via shfl_xor.
__device__ __forceinline__ float fid_half(const int p, const h2 a[8], const v2f x[8],
                                          const float dz[NQ]) {
  v2f ph[NQ];
#pragma unroll
  for (int q = 0; q < NQ; ++q) {
    float s, c; sincos_hw(dz[q] * INV2PI, s, c);
    ph[q] = mk2(c, s);
  }
  v2f d[8];
#pragma unroll
  for (int m = 0; m < 8; ++m) {
    const float ar = (float)a[m].x, ai = (float)a[m].y;
    d[m] = mk2(ar * x[m].x + ai * x[m].y, ar * x[m].y - ai * x[m].x);
  }
  // contract b0 (qubit3 -> ph[3]), then b1 (ph[2]), then b2 (ph[1])
  v2f e0 = d[0] + cmul(d[1], ph[3]);
  v2f e1 = d[2] + cmul(d[3], ph[3]);
  v2f e2 = d[4] + cmul(d[5], ph[3]);
  v2f e3 = d[6] + cmul(d[7], ph[3]);
  v2f f0 = e0 + cmul(e1, ph[2]);
  v2f f1 = e2 + cmul(e3, ph[2]);
  v2f g  = f0 + cmul(f1, ph[1]);
  // qubit0 phase on the p==1 half, then cross-lane sum
  const v2f gp = cmul(g, ph[0]);
  const v2f P  = p ? gp : g;
  const v2f ov = mk2(P.x + __shfl_xor(P.x, 1), P.y + __shfl_xor(P.y, 1));
  return ov.x * ov.x + ov.y * ov.y;
}

__device__ __forceinline__ void load8(const float* __restrict__ p, int b, float a[8]) {
  const float4* v = reinterpret_cast<const float4*>(p) + (size_t)b * 2;
  float4 x0 = v[0], x1 = v[1];
  a[0]=x0.x; a[1]=x0.y; a[2]=x0.z; a[3]=x0.w;
  a[4]=x1.x; a[5]=x1.y; a[6]=x1.z; a[7]=x1.w;
}

__global__ __launch_bounds__(256) void triplet_main(
    const float* __restrict__ a_ry, const float* __restrict__ a_rz,
    const float* __restrict__ p_ry, const float* __restrict__ p_rz,
    const float* __restrict__ n_ry, const float* __restrict__ n_rz,
    float* __restrict__ block_sums, int batch) {
  const int g = blockIdx.x * blockDim.x + threadIdx.x;
  const int b = g >> 1;
  const int p = g & 1;

  float loss = 0.0f;
  if (b < batch) {
    float ry[8], rz[8], arz2[NQ];

    // anchor half, packed to f16 (validated: absmax 0 in round 10)
    load8(a_ry, b, ry); load8(a_rz, b, rz);
#pragma unroll
    for (int q = 0; q < NQ; ++q) arz2[q] = rz[4 + q];
    h2 ah[8];
    {
      v2f tmp[8];
      sim_half(p, ry, rz, tmp);
#pragma unroll
      for (int m = 0; m < 8; ++m) {
        h2 v; v.x = (_Float16)tmp[m].x; v.y = (_Float16)tmp[m].y;
        ah[m] = v;
      }
    }

    // positive half
    load8(p_ry, b, ry); load8(p_rz, b, rz);
    v2f xs[8];
    sim_half(p, ry, rz, xs);
    float dz[NQ];
#pragma unroll
    for (int q = 0; q < NQ; ++q) dz[q] = rz[4 + q] - arz2[q];
    const float fid_pos = fid_half(p, ah, xs, dz);

    // negative half (reuse xs)
    load8(n_ry, b, ry); load8(n_rz, b, rz);
    sim_half(p, ry, rz, xs);
#pragma unroll
    for (int q = 0; q < NQ; ++q) dz[q] = rz[4 + q] - arz2[q];
    const float fid_neg = fid_half(p, ah, xs, dz);

    loss = fmaxf(MARGIN - fid_pos + fid_neg, 0.0f);   // identical in both lanes
  }

  // wave (64) reduce, then LDS across the 4 waves
#pragma unroll
  for (int off = 32; off >= 1; off >>= 1)
    loss += __shfl_down(loss, off, 64);

  __shared__ float wsum[4];
  const int lane = threadIdx.x & 63;
  const int wid  = threadIdx.x >> 6;
  if (lane == 0) wsum[wid] = loss;
  __syncthreads();
  if (threadIdx.x == 0) {
    block_sums[blockIdx.x] = wsum[0] + wsum[1] + wsum[2] + wsum[3];
  }
}

__global__ __launch_bounds__(256) void triplet_reduce(
    const float* __restrict__ block_sums, int nblocks, float* __restrict__ out, float inv_2batch) {
  float s = 0.0f;
  for (int i = threadIdx.x; i < nblocks; i += 256) s += block_sums[i];
#pragma unroll
  for (int off = 32; off >= 1; off >>= 1)
    s += __shfl_down(s, off, 64);

  __shared__ float wsum[4];
  const int lane = threadIdx.x & 63;
  const int wid  = threadIdx.x >> 6;
  if (lane == 0) wsum[wid] = s;
  __syncthreads();
  if (threadIdx.x == 0) {
    out[0] = (wsum[0] + wsum[1] + wsum[2] + wsum[3]) * inv_2batch;
  }
}

extern "C" void kernel_launch(void* const* d_in, const int* in_sizes, int n_in,
                              void* d_out, int out_size, void* d_ws, size_t ws_size,
                              hipStream_t stream) {
  const float* a_ry = (const float*)d_in[0];
  const float* a_rz = (const float*)d_in[1];
  const float* p_ry = (const float*)d_in[2];
  const float* p_rz = (const float*)d_in[3];
  const float* n_ry = (const float*)d_in[4];
  const float* n_rz = (const float*)d_in[5];
  float* out = (float*)d_out;

  const int batch = in_sizes[0] / 8;                 // NL*NQ = 8 angles per element
  const int nthreads = batch * 2;                    // 2 lanes per element
  const int nblocks = (nthreads + 255) / 256;        // 4096
  float* block_sums = (float*)d_ws;

  triplet_main<<<nblocks, 256, 0, stream>>>(a_ry, a_rz, p_ry, p_rz, n_ry, n_rz,
                                            block_sums, batch);
  triplet_reduce<<<1, 256, 0, stream>>>(block_sums, nblocks, out,
                                        1.0f / (2.0f * (float)batch));
}

// Round 12
// 29.492 us; speedup vs baseline: 3.0065x; 1.3391x over previous
//
#include <hip/hip_runtime.h>

typedef float v2f __attribute__((ext_vector_type(2)));

constexpr int NQ = 4;
constexpr int DIM = 16;          // 2^NQ
constexpr float MARGIN = 0.3f;
constexpr float INV2PI = 0.15915494309189535f;

__device__ __forceinline__ v2f mk2(float x, float y) { v2f r; r.x = x; r.y = y; return r; }
__device__ __forceinline__ v2f splat(float x) { return mk2(x, x); }

// Packed f32 math (VOP3P, 2 floats per instruction, even-aligned VGPR pairs).
// hipcc scalarizes v2f arithmetic; force selection via inline asm.
__device__ __forceinline__ v2f pk_mul(v2f a, v2f b) {
  v2f d; asm("v_pk_mul_f32 %0, %1, %2" : "=v"(d) : "v"(a), "v"(b)); return d;
}
__device__ __forceinline__ v2f pk_fma(v2f a, v2f b, v2f c) {
  v2f d; asm("v_pk_fma_f32 %0, %1, %2, %3" : "=v"(d) : "v"(a), "v"(b), "v"(c)); return d;
}

// complex multiply a*b where bs = {-b.y, b.x} is precomputed (cross-half: scalar).
__device__ __forceinline__ v2f cmul_pre(v2f a, v2f b, v2f bs) {
  return a.xx * b + a.yy * bs;
}

__device__ __forceinline__ void sincos_hw(float rev, float& s, float& c) {
  s = __builtin_amdgcn_sinf(rev);   // input in revolutions
  c = __builtin_amdgcn_cosf(rev);
}

// CNOT ladder CNOT(q,q+1), q=0..2; qubit q == flat bit (3-q). Free permutation.
__device__ __forceinline__ void cnot_ladder(v2f s[DIM]) {
#pragma unroll
  for (int q = 0; q < NQ - 1; ++q) {
    const int pc = 1 << (NQ - 1 - q);
    const int pt = 1 << (NQ - 2 - q);
#pragma unroll
    for (int i = 0; i < DIM; ++i) {
      if ((i & pc) && !(i & pt)) {
        const int j = i | pt;
        v2f t = s[i]; s[i] = s[j]; s[j] = t;
      }
    }
  }
}

// Layer-1 product state (RZ as diag(1,e^{i z}), global phase dropped) + CNOT
// ladder + layer-2 RY butterflies (packed). Final RZ merged into the overlap;
// final CNOT ladder cancels in the overlap.
__device__ __forceinline__ void sim_core(const float ry[8], const float rz[8], v2f s[DIM]) {
  float c0[NQ]; v2f p1[NQ], p1s[NQ];
#pragma unroll
  for (int q = 0; q < NQ; ++q) {
    float sy, cy; sincos_hw(ry[q] * (0.5f * INV2PI), sy, cy);
    float sz, cz; sincos_hw(rz[q] * INV2PI, sz, cz);
    c0[q]  = cy;
    p1[q]  = mk2(sy * cz, sy * sz);
    p1s[q] = mk2(-p1[q].y, p1[q].x);
  }
  // tensor-product tree; qubit q is flat bit (3-q)
  v2f t2[4];
  t2[0] = mk2(c0[0] * c0[1], 0.0f);
  t2[1] = pk_mul(splat(c0[0]), p1[1]);
  t2[2] = pk_mul(splat(c0[1]), p1[0]);
  t2[3] = cmul_pre(p1[0], p1[1], p1s[1]);
  v2f t3[8];
  {
    const v2f c2v = splat(c0[2]);
#pragma unroll
    for (int k = 0; k < 4; ++k) {
      t3[2*k]   = pk_mul(t2[k], c2v);
      t3[2*k+1] = cmul_pre(t2[k], p1[2], p1s[2]);
    }
  }
  {
    const v2f c3v = splat(c0[3]);
#pragma unroll
    for (int k = 0; k < 8; ++k) {
      s[2*k]   = pk_mul(t3[k], c3v);
      s[2*k+1] = cmul_pre(t3[k], p1[3], p1s[3]);
    }
  }

  cnot_ladder(s);

  // layer-2 RY butterflies: packed (2 pk_mul + 2 pk_fma per pair vs 8 scalar)
#pragma unroll
  for (int q = 0; q < NQ; ++q) {
    const int bit = 1 << (NQ - 1 - q);
    float sy, cy; sincos_hw(ry[4 + q] * (0.5f * INV2PI), sy, cy);
    const v2f cyv = splat(cy), syv = splat(sy), nsyv = splat(-sy);
#pragma unroll
    for (int i = 0; i < DIM; ++i) {
      if (i & bit) continue;
      const int j = i | bit;
      const v2f a0 = s[i], a1 = s[j];
      s[i] = pk_fma(a1, nsyv, pk_mul(a0, cyv));   // cy*a0 - sy*a1
      s[j] = pk_fma(a0, syv,  pk_mul(a1, cyv));   // sy*a0 + cy*a1
    }
  }
}

// |<a| PΔ |x>|^2 with PΔ = ⊗_q diag(1, e^{i dz_q}) folded into the dot via a
// per-qubit contraction tree (cross-half complex ops: scalar).
__device__ __forceinline__ float fid_tree(const v2f a[DIM], const v2f x[DIM],
                                          const float dz[NQ]) {
  v2f ph[NQ], phs[NQ];
#pragma unroll
  for (int q = 0; q < NQ; ++q) {
    float s, c; sincos_hw(dz[q] * INV2PI, s, c);
    ph[q] = mk2(c, s); phs[q] = mk2(-s, c);
  }
  v2f d[DIM];
#pragma unroll
  for (int i = 0; i < DIM; ++i) {
    d[i] = mk2(a[i].x * x[i].x + a[i].y * x[i].y,
               a[i].x * x[i].y - a[i].y * x[i].x);
  }
  v2f e[8];
#pragma unroll
  for (int j = 0; j < 8; ++j) e[j] = d[2*j] + cmul_pre(d[2*j+1], ph[3], phs[3]);
  v2f f[4];
#pragma unroll
  for (int k = 0; k < 4; ++k) f[k] = e[2*k] + cmul_pre(e[2*k+1], ph[2], phs[2]);
  v2f g[2];
#pragma unroll
  for (int m = 0; m < 2; ++m) g[m] = f[2*m] + cmul_pre(f[2*m+1], ph[1], phs[1]);
  const v2f ov = g[0] + cmul_pre(g[1], ph[0], phs[0]);
  return ov.x * ov.x + ov.y * ov.y;
}

__device__ __forceinline__ void load8(const float* __restrict__ p, int b, float a[8]) {
  const float4* v = reinterpret_cast<const float4*>(p) + (size_t)b * 2;
  float4 x0 = v[0], x1 = v[1];
  a[0]=x0.x; a[1]=x0.y; a[2]=x0.z; a[3]=x0.w;
  a[4]=x1.x; a[5]=x1.y; a[6]=x1.z; a[7]=x1.w;
}

__global__ __launch_bounds__(256) void triplet_main(
    const float* __restrict__ a_ry, const float* __restrict__ a_rz,
    const float* __restrict__ p_ry, const float* __restrict__ p_rz,
    const float* __restrict__ n_ry, const float* __restrict__ n_rz,
    float* __restrict__ block_sums, int batch) {
  const int b = blockIdx.x * blockDim.x + threadIdx.x;

  float loss = 0.0f;
  if (b < batch) {
    float ry[8], rz[8], arz2[NQ];

    // anchor (final RZ merged into the dots, final CNOT ladder cancelled)
    load8(a_ry, b, ry); load8(a_rz, b, rz);
#pragma unroll
    for (int q = 0; q < NQ; ++q) arz2[q] = rz[4 + q];
    v2f as[DIM];
    sim_core(ry, rz, as);

    // positive
    load8(p_ry, b, ry); load8(p_rz, b, rz);
    v2f xs[DIM];
    sim_core(ry, rz, xs);
    float dz[NQ];
#pragma unroll
    for (int q = 0; q < NQ; ++q) dz[q] = rz[4 + q] - arz2[q];
    const float fid_pos = fid_tree(as, xs, dz);

    // negative (reuse xs)
    load8(n_ry, b, ry); load8(n_rz, b, rz);
    sim_core(ry, rz, xs);
#pragma unroll
    for (int q = 0; q < NQ; ++q) dz[q] = rz[4 + q] - arz2[q];
    const float fid_neg = fid_tree(as, xs, dz);

    loss = fmaxf(MARGIN - fid_pos + fid_neg, 0.0f);
  }

  // wave (64) reduce, then LDS across the 4 waves
#pragma unroll
  for (int off = 32; off >= 1; off >>= 1)
    loss += __shfl_down(loss, off, 64);

  __shared__ float wsum[4];
  const int lane = threadIdx.x & 63;
  const int wid  = threadIdx.x >> 6;
  if (lane == 0) wsum[wid] = loss;
  __syncthreads();
  if (threadIdx.x == 0) {
    block_sums[blockIdx.x] = wsum[0] + wsum[1] + wsum[2] + wsum[3];
  }
}

__global__ __launch_bounds__(256) void triplet_reduce(
    const float* __restrict__ block_sums, int nblocks, float* __restrict__ out, float inv_batch) {
  float s = 0.0f;
  for (int i = threadIdx.x; i < nblocks; i += 256) s += block_sums[i];
#pragma unroll
  for (int off = 32; off >= 1; off >>= 1)
    s += __shfl_down(s, off, 64);

  __shared__ float wsum[4];
  const int lane = threadIdx.x & 63;
  const int wid  = threadIdx.x >> 6;
  if (lane == 0) wsum[wid] = s;
  __syncthreads();
  if (threadIdx.x == 0) {
    out[0] = (wsum[0] + wsum[1] + wsum[2] + wsum[3]) * inv_batch;
  }
}

extern "C" void kernel_launch(void* const* d_in, const int* in_sizes, int n_in,
                              void* d_out, int out_size, void* d_ws, size_t ws_size,
                              hipStream_t stream) {
  const float* a_ry = (const float*)d_in[0];
  const float* a_rz = (const float*)d_in[1];
  const float* p_ry = (const float*)d_in[2];
  const float* p_rz = (const float*)d_in[3];
  const float* n_ry = (const float*)d_in[4];
  const float* n_rz = (const float*)d_in[5];
  float* out = (float*)d_out;

  const int batch = in_sizes[0] / 8;            // NL*NQ = 8 angles per element
  const int nblocks = (batch + 255) / 256;      // 2048
  float* block_sums = (float*)d_ws;

  triplet_main<<<nblocks, 256, 0, stream>>>(a_ry, a_rz, p_ry, p_rz, n_ry, n_rz,
                                            block_sums, batch);
  triplet_reduce<<<1, 256, 0, stream>>>(block_sums, nblocks, out, 1.0f / (float)batch);
}

// Round 13
// 27.967 us; speedup vs baseline: 3.1704x; 1.0545x over previous
//
#include <hip/hip_runtime.h>

typedef float v2f __attribute__((ext_vector_type(2)));

constexpr int NQ = 4;
constexpr int DIM = 16;          // 2^NQ
constexpr float MARGIN = 0.3f;
constexpr float INV2PI = 0.15915494309189535f;

__device__ __forceinline__ v2f mk2(float x, float y) { v2f r; r.x = x; r.y = y; return r; }

__device__ __forceinline__ void sincos_hw(float rev, float& s, float& c) {
  s = __builtin_amdgcn_sinf(rev);   // input in revolutions
  c = __builtin_amdgcn_cosf(rev);
}

// ---------- VOP3P packed-f32 complex primitives ----------
// A v2f is an even-aligned VGPR pair (lo=re, hi=im). op_sel picks which 32-bit
// reg of each source feeds the lo-half op; op_sel_hi the hi-half op; neg_lo/
// neg_hi negate per-half sources. Swizzles/conj/broadcasts are free.

// a*b (complex), 2 instrs
__device__ __forceinline__ v2f cmul(v2f a, v2f b) {
  v2f t, d;
  asm("v_pk_mul_f32 %0, %1, %2 op_sel:[0,0] op_sel_hi:[0,1]"
      : "=v"(t) : "v"(a), "v"(b));                       // (a.re*b.re, a.re*b.im)
  asm("v_pk_fma_f32 %0, %1, %2, %3 op_sel:[1,1,0] op_sel_hi:[1,0,1] neg_lo:[1,0,0]"
      : "=v"(d) : "v"(a), "v"(b), "v"(t));               // (-a.im*b.im+t.lo, a.im*b.re+t.hi)
  return d;
}
// c + a*b (complex), 2 instrs
__device__ __forceinline__ v2f cmadd(v2f a, v2f b, v2f c) {
  v2f t, d;
  asm("v_pk_fma_f32 %0, %1, %2, %3 op_sel:[0,0,0] op_sel_hi:[0,1,1]"
      : "=v"(t) : "v"(a), "v"(b), "v"(c));               // (a.re*b.re+c.re, a.re*b.im+c.im)
  asm("v_pk_fma_f32 %0, %1, %2, %3 op_sel:[1,1,0] op_sel_hi:[1,0,1] neg_lo:[1,0,0]"
      : "=v"(d) : "v"(a), "v"(b), "v"(t));
  return d;
}
// conj(a)*x, 2 instrs
__device__ __forceinline__ v2f cjmul(v2f a, v2f x) {
  v2f t, d;
  asm("v_pk_mul_f32 %0, %1, %2 op_sel:[0,0] op_sel_hi:[0,1]"
      : "=v"(t) : "v"(a), "v"(x));                       // (a.re*x.re, a.re*x.im)
  asm("v_pk_fma_f32 %0, %1, %2, %3 op_sel:[1,1,0] op_sel_hi:[1,0,1] neg_hi:[1,0,0]"
      : "=v"(d) : "v"(a), "v"(x), "v"(t));               // (a.im*x.im+t.lo, -a.im*x.re+t.hi)
  return d;
}
// real scalar (cs.lo) * complex b, 1 instr
__device__ __forceinline__ v2f rmul_lo(v2f cs, v2f b) {
  v2f d;
  asm("v_pk_mul_f32 %0, %1, %2 op_sel:[0,0] op_sel_hi:[0,1]" : "=v"(d) : "v"(cs), "v"(b));
  return d;
}
// real scalar (cs.hi) * complex b, 1 instr
__device__ __forceinline__ v2f rmul_hi(v2f cs, v2f b) {
  v2f d;
  asm("v_pk_mul_f32 %0, %1, %2 op_sel:[1,0] op_sel_hi:[1,1]" : "=v"(d) : "v"(cs), "v"(b));
  return d;
}
// RY butterfly, cs=(cy,sy): s0' = cy*s0 - sy*s1 ; s1' = sy*s0 + cy*s1 (4 instrs)
__device__ __forceinline__ void bfly(v2f cs, v2f& s0, v2f& s1) {
  v2f t, u, r0, r1;
  asm("v_pk_mul_f32 %0, %1, %2 op_sel:[0,0] op_sel_hi:[0,1]"
      : "=v"(t) : "v"(cs), "v"(s0));                     // cy*s0
  asm("v_pk_mul_f32 %0, %1, %2 op_sel:[1,0] op_sel_hi:[1,1]"
      : "=v"(u) : "v"(cs), "v"(s0));                     // sy*s0
  asm("v_pk_fma_f32 %0, %1, %2, %3 op_sel:[1,0,0] op_sel_hi:[1,1,1] neg_lo:[1,0,0] neg_hi:[1,0,0]"
      : "=v"(r0) : "v"(cs), "v"(s1), "v"(t));            // -sy*s1 + cy*s0
  asm("v_pk_fma_f32 %0, %1, %2, %3 op_sel:[0,0,0] op_sel_hi:[0,1,1]"
      : "=v"(r1) : "v"(cs), "v"(s1), "v"(u));            // cy*s1 + sy*s0
  s0 = r0; s1 = r1;
}

// CNOT ladder CNOT(q,q+1), q=0..2; qubit q == flat bit (3-q). Free permutation.
__device__ __forceinline__ void cnot_ladder(v2f s[DIM]) {
#pragma unroll
  for (int q = 0; q < NQ - 1; ++q) {
    const int pc = 1 << (NQ - 1 - q);
    const int pt = 1 << (NQ - 2 - q);
#pragma unroll
    for (int i = 0; i < DIM; ++i) {
      if ((i & pc) && !(i & pt)) {
        const int j = i | pt;
        v2f t = s[i]; s[i] = s[j]; s[j] = t;
      }
    }
  }
}

// Layer-1 product state (RZ as diag(1,e^{i z}), global phase dropped) + CNOT
// ladder + layer-2 RY butterflies — fully packed. Final RZ merged into the
// overlap; final CNOT ladder cancels in the overlap.
__device__ __forceinline__ void sim_core(const float ry[8], const float rz[8], v2f s[DIM]) {
  v2f cs[NQ], p1[NQ];
#pragma unroll
  for (int q = 0; q < NQ; ++q) {
    float sy, cy; sincos_hw(ry[q] * (0.5f * INV2PI), sy, cy);
    float sz, cz; sincos_hw(rz[q] * INV2PI, sz, cz);
    cs[q] = mk2(cy, sy);
    p1[q] = rmul_hi(cs[q], mk2(cz, sz));     // (sy*cz, sy*sz)
  }
  v2f t2[4];
  t2[0] = mk2(cs[0].x * cs[1].x, 0.0f);
  t2[1] = rmul_lo(cs[0], p1[1]);
  t2[2] = rmul_lo(cs[1], p1[0]);
  t2[3] = cmul(p1[0], p1[1]);
  v2f t3[8];
#pragma unroll
  for (int k = 0; k < 4; ++k) {
    t3[2*k]   = rmul_lo(cs[2], t2[k]);
    t3[2*k+1] = cmul(t2[k], p1[2]);
  }
#pragma unroll
  for (int k = 0; k < 8; ++k) {
    s[2*k]   = rmul_lo(cs[3], t3[k]);
    s[2*k+1] = cmul(t3[k], p1[3]);
  }

  cnot_ladder(s);

  // layer-2 RY butterflies (packed, (cy,sy) in one pair, no splats)
#pragma unroll
  for (int q = 0; q < NQ; ++q) {
    const int bit = 1 << (NQ - 1 - q);
    float sy, cy; sincos_hw(ry[4 + q] * (0.5f * INV2PI), sy, cy);
    const v2f c2 = mk2(cy, sy);
#pragma unroll
    for (int i = 0; i < DIM; ++i) {
      if (i & bit) continue;
      bfly(c2, s[i], s[i | bit]);
    }
  }
}

// |<a| PΔ |x>|^2 with PΔ = ⊗_q diag(1, e^{i dz_q}) folded into the dot via the
// per-qubit contraction tree — fully packed (2 instrs per complex op).
__device__ __forceinline__ float fid_tree(const v2f a[DIM], const v2f x[DIM],
                                          const float dz[NQ]) {
  v2f ph[NQ];
#pragma unroll
  for (int q = 0; q < NQ; ++q) {
    float s, c; sincos_hw(dz[q] * INV2PI, s, c);
    ph[q] = mk2(c, s);
  }
  v2f e[8];
#pragma unroll
  for (int j = 0; j < 8; ++j) {
    const v2f d0 = cjmul(a[2*j],   x[2*j]);
    const v2f d1 = cjmul(a[2*j+1], x[2*j+1]);
    e[j] = cmadd(d1, ph[3], d0);
  }
  v2f f[4];
#pragma unroll
  for (int k = 0; k < 4; ++k) f[k] = cmadd(e[2*k+1], ph[2], e[2*k]);
  v2f g[2];
#pragma unroll
  for (int m = 0; m < 2; ++m) g[m] = cmadd(f[2*m+1], ph[1], f[2*m]);
  const v2f ov = cmadd(g[1], ph[0], g[0]);
  return ov.x * ov.x + ov.y * ov.y;
}

__device__ __forceinline__ void load8(const float* __restrict__ p, int b, float a[8]) {
  const float4* v = reinterpret_cast<const float4*>(p) + (size_t)b * 2;
  float4 x0 = v[0], x1 = v[1];
  a[0]=x0.x; a[1]=x0.y; a[2]=x0.z; a[3]=x0.w;
  a[4]=x1.x; a[5]=x1.y; a[6]=x1.z; a[7]=x1.w;
}

__global__ __launch_bounds__(256) void triplet_main(
    const float* __restrict__ a_ry, const float* __restrict__ a_rz,
    const float* __restrict__ p_ry, const float* __restrict__ p_rz,
    const float* __restrict__ n_ry, const float* __restrict__ n_rz,
    float* __restrict__ block_sums, int batch) {
  const int b = blockIdx.x * blockDim.x + threadIdx.x;

  float loss = 0.0f;
  if (b < batch) {
    float ry[8], rz[8], arz2[NQ];

    // anchor (final RZ merged into the dots, final CNOT ladder cancelled)
    load8(a_ry, b, ry); load8(a_rz, b, rz);
#pragma unroll
    for (int q = 0; q < NQ; ++q) arz2[q] = rz[4 + q];
    v2f as[DIM];
    sim_core(ry, rz, as);

    // positive
    load8(p_ry, b, ry); load8(p_rz, b, rz);
    v2f xs[DIM];
    sim_core(ry, rz, xs);
    float dz[NQ];
#pragma unroll
    for (int q = 0; q < NQ; ++q) dz[q] = rz[4 + q] - arz2[q];
    const float fid_pos = fid_tree(as, xs, dz);

    // negative (reuse xs)
    load8(n_ry, b, ry); load8(n_rz, b, rz);
    sim_core(ry, rz, xs);
#pragma unroll
    for (int q = 0; q < NQ; ++q) dz[q] = rz[4 + q] - arz2[q];
    const float fid_neg = fid_tree(as, xs, dz);

    loss = fmaxf(MARGIN - fid_pos + fid_neg, 0.0f);
  }

  // wave (64) reduce, then LDS across the 4 waves
#pragma unroll
  for (int off = 32; off >= 1; off >>= 1)
    loss += __shfl_down(loss, off, 64);

  __shared__ float wsum[4];
  const int lane = threadIdx.x & 63;
  const int wid  = threadIdx.x >> 6;
  if (lane == 0) wsum[wid] = loss;
  __syncthreads();
  if (threadIdx.x == 0) {
    block_sums[blockIdx.x] = wsum[0] + wsum[1] + wsum[2] + wsum[3];
  }
}

__global__ __launch_bounds__(256) void triplet_reduce(
    const float* __restrict__ block_sums, int nblocks, float* __restrict__ out, float inv_batch) {
  float s = 0.0f;
  for (int i = threadIdx.x; i < nblocks; i += 256) s += block_sums[i];
#pragma unroll
  for (int off = 32; off >= 1; off >>= 1)
    s += __shfl_down(s, off, 64);

  __shared__ float wsum[4];
  const int lane = threadIdx.x & 63;
  const int wid  = threadIdx.x >> 6;
  if (lane == 0) wsum[wid] = s;
  __syncthreads();
  if (threadIdx.x == 0) {
    out[0] = (wsum[0] + wsum[1] + wsum[2] + wsum[3]) * inv_batch;
  }
}

extern "C" void kernel_launch(void* const* d_in, const int* in_sizes, int n_in,
                              void* d_out, int out_size, void* d_ws, size_t ws_size,
                              hipStream_t stream) {
  const float* a_ry = (const float*)d_in[0];
  const float* a_rz = (const float*)d_in[1];
  const float* p_ry = (const float*)d_in[2];
  const float* p_rz = (const float*)d_in[3];
  const float* n_ry = (const float*)d_in[4];
  const float* n_rz = (const float*)d_in[5];
  float* out = (float*)d_out;

  const int batch = in_sizes[0] / 8;            // NL*NQ = 8 angles per element
  const int nblocks = (batch + 255) / 256;      // 2048
  float* block_sums = (float*)d_ws;

  triplet_main<<<nblocks, 256, 0, stream>>>(a_ry, a_rz, p_ry, p_rz, n_ry, n_rz,
                                            block_sums, batch);
  triplet_reduce<<<1, 256, 0, stream>>>(block_sums, nblocks, out, 1.0f / (float)batch);
}